// Round 1
// baseline (310.025 us; speedup 1.0000x reference)
//
#include <hip/hip_runtime.h>
#include <math.h>

// GaussianPMIModel: mean/cov over X_train (50000x32 f32), then for each eval
// point (100000x32) and each of the 496 (i<j) pairs compute
// exp(lp_diag - lp_full) for the 2x2 Gaussian; output (100000, 529) f32 with
// first 33 columns == 1.0.
//
// Closed form per pair: val = exp(A*dxi^2 + B*dxj^2 + C*dxi*dxj + K) with
//   det = vi*vj - c^2, A = 0.5*c^2/(vi*det), B = 0.5*c^2/(vj*det),
//   C = -c/det, K = 0.5*log(det/(vi*vj)).   (log(2pi) terms cancel.)

#define D       32
#define NPAIRS  496
#define NTRAIN  50000
#define NEVAL   100000
#define OUTC    529          // 1 + 32 + 496
#define ROWS_PB 16           // eval rows per block in main kernel
#define COV_CHUNK 256        // train rows per block in cov kernel
#define MEAN_CHUNK 512       // train rows per block in mean kernel

// ws float layout:
//   [0,32)       column sums (atomic)
//   [32,560)     cov sums: diag at 32+i, pair p at 64+p (atomic)
//   [560,1056)   A
//   [1056,1552)  B
//   [1552,2048)  C
//   [2048,2544)  K
//   [2544,3040)  packed (i | j<<8), stored as int
//   [3040,3072)  mean

__global__ void zero_ws_kernel(float* ws) {
    int t = blockIdx.x * blockDim.x + threadIdx.x;
    if (t < 560) ws[t] = 0.0f;
}

__global__ __launch_bounds__(256) void mean_kernel(const float* __restrict__ X,
                                                   float* __restrict__ ws) {
    __shared__ float sdata[256];
    int t = threadIdx.x;
    int col = t & 31;
    int rowoff = t >> 5;                       // 0..7 -> 8 rows per sweep, coalesced
    int base = blockIdx.x * MEAN_CHUNK;
    float s = 0.0f;
    for (int r = rowoff; r < MEAN_CHUNK; r += 8) {
        int row = base + r;
        if (row < NTRAIN) s += X[row * D + col];
    }
    sdata[t] = s;
    __syncthreads();
    if (t < 32) {
        float tot = 0.0f;
        #pragma unroll
        for (int w = 0; w < 8; ++w) tot += sdata[t + 32 * w];
        atomicAdd(&ws[t], tot);
    }
}

static __device__ __forceinline__ void emit_cov(float* ws, int i, int j, float v) {
    if (i > j) return;                         // each (i<=j) entry emitted exactly once
    if (i == j) {
        atomicAdd(&ws[32 + i], v);
    } else {
        int p = i * 31 - (i * (i - 1)) / 2 + (j - i - 1);   // combinations order
        atomicAdd(&ws[64 + p], v);
    }
}

__global__ __launch_bounds__(256) void cov_kernel(const float* __restrict__ X,
                                                  float* __restrict__ ws) {
    __shared__ float xs[64 * D];               // 8 KB tile of centered rows
    __shared__ float smean[D];
    int t = threadIdx.x;
    if (t < D) smean[t] = ws[t] * (1.0f / NTRAIN);
    __syncthreads();

    // thread (ti,tj) owns the 2x2 tile rows {2ti,2ti+1} x cols {2tj,2tj+1}
    int ti = t >> 4, tj = t & 15;
    float a00 = 0.f, a01 = 0.f, a10 = 0.f, a11 = 0.f;
    int base = blockIdx.x * COV_CHUNK;

    for (int tile = 0; tile < COV_CHUNK; tile += 64) {
        for (int e = t; e < 64 * D; e += 256) {
            int r = e >> 5, c = e & 31;
            int row = base + tile + r;
            xs[e] = (row < NTRAIN) ? (X[row * D + c] - smean[c]) : 0.0f;
        }
        __syncthreads();
        #pragma unroll 4
        for (int r = 0; r < 64; ++r) {
            float xi0 = xs[r * D + 2 * ti];
            float xi1 = xs[r * D + 2 * ti + 1];
            float xj0 = xs[r * D + 2 * tj];
            float xj1 = xs[r * D + 2 * tj + 1];
            a00 += xi0 * xj0; a01 += xi0 * xj1;
            a10 += xi1 * xj0; a11 += xi1 * xj1;
        }
        __syncthreads();
    }
    int i0 = 2 * ti, i1 = 2 * ti + 1, j0 = 2 * tj, j1 = 2 * tj + 1;
    emit_cov(ws, i0, j0, a00);
    emit_cov(ws, i0, j1, a01);
    emit_cov(ws, i1, j0, a10);
    emit_cov(ws, i1, j1, a11);
}

__global__ void prep_kernel(float* ws) {
    int t = threadIdx.x;
    if (t < D) ws[3040 + t] = ws[t] * (1.0f / NTRAIN);
    if (t < NPAIRS) {
        // map p -> (i, j), combinations(range(32), 2) order
        int i = 0, rem = t;
        while (rem >= 31 - i) { rem -= 31 - i; ++i; }
        int j = i + 1 + rem;
        const float inv_nm1 = 1.0f / (float)(NTRAIN - 1);
        float vi = ws[32 + i] * inv_nm1;
        float vj = ws[32 + j] * inv_nm1;
        float c  = ws[64 + t] * inv_nm1;
        float det = vi * vj - c * c;
        float invdet = 1.0f / det;
        ws[560  + t] = 0.5f * c * c * invdet / vi;   // A
        ws[1056 + t] = 0.5f * c * c * invdet / vj;   // B
        ws[1552 + t] = -c * invdet;                  // C
        ws[2048 + t] = 0.5f * logf(det / (vi * vj)); // K
        ((int*)ws)[2544 + t] = i | (j << 8);
    }
}

__global__ __launch_bounds__(256) void pmi_kernel(const float* __restrict__ x,
                                                  const float* __restrict__ ws,
                                                  float* __restrict__ out) {
    __shared__ float cA[NPAIRS], cB[NPAIRS], cC[NPAIRS], cK[NPAIRS];
    __shared__ int   cIJ[NPAIRS];
    __shared__ float smean[D];
    __shared__ float dx[ROWS_PB * D];
    int t = threadIdx.x;

    for (int p = t; p < NPAIRS; p += 256) {
        cA[p]  = ws[560 + p];
        cB[p]  = ws[1056 + p];
        cC[p]  = ws[1552 + p];
        cK[p]  = ws[2048 + p];
        cIJ[p] = ((const int*)ws)[2544 + p];
    }
    if (t < D) smean[t] = ws[3040 + t];
    __syncthreads();

    int rowbase = blockIdx.x * ROWS_PB;        // grid is exact: 100000/16 = 6250
    for (int e = t; e < ROWS_PB * D; e += 256) {
        int r = e >> 5, c = e & 31;
        dx[e] = x[(size_t)(rowbase + r) * D + c] - smean[c];
    }
    __syncthreads();

    // ROWS_PB*529 = 8464 outputs = 2116 float4, contiguous & 16B-aligned.
    float4* out4 = (float4*)(out + (size_t)rowbase * OUTC);
    const int NF4 = ROWS_PB * OUTC / 4;
    for (int f = t; f < NF4; f += 256) {
        int e = 4 * f;
        int r = (int)((unsigned)e / OUTC);
        int k = e - r * OUTC;
        float v[4];
        #pragma unroll
        for (int q = 0; q < 4; ++q) {
            float val;
            if (k < 33) {
                val = 1.0f;
            } else {
                int p = k - 33;
                int ij = cIJ[p];
                int i = ij & 255, j = ij >> 8;
                float dxi = dx[r * D + i];
                float dxj = dx[r * D + j];
                val = __expf(cA[p] * dxi * dxi + cB[p] * dxj * dxj +
                             cC[p] * dxi * dxj + cK[p]);
            }
            v[q] = val;
            if (++k == OUTC) { k = 0; ++r; }
        }
        out4[f] = make_float4(v[0], v[1], v[2], v[3]);
    }
}

extern "C" void kernel_launch(void* const* d_in, const int* in_sizes, int n_in,
                              void* d_out, int out_size, void* d_ws, size_t ws_size,
                              hipStream_t stream) {
    const float* X = (const float*)d_in[0];   // X_train (50000, 32) f32
    const float* x = (const float*)d_in[1];   // x       (100000, 32) f32
    float* out = (float*)d_out;               // (100000, 529) f32
    float* ws  = (float*)d_ws;

    hipLaunchKernelGGL(zero_ws_kernel, dim3(3), dim3(256), 0, stream, ws);
    hipLaunchKernelGGL(mean_kernel, dim3((NTRAIN + MEAN_CHUNK - 1) / MEAN_CHUNK),
                       dim3(256), 0, stream, X, ws);
    hipLaunchKernelGGL(cov_kernel, dim3((NTRAIN + COV_CHUNK - 1) / COV_CHUNK),
                       dim3(256), 0, stream, X, ws);
    hipLaunchKernelGGL(prep_kernel, dim3(1), dim3(512), 0, stream, ws);
    hipLaunchKernelGGL(pmi_kernel, dim3(NEVAL / ROWS_PB), dim3(256), 0, stream,
                       x, ws, out);
}